// Round 11
// baseline (444.888 us; speedup 1.0000x reference)
//
#include <hip/hip_runtime.h>
#include <math.h>

// GatedCrossAttentionFusion on MI355X (gfx950), bf16 MFMA pipeline.
// B=16384, VD=2048, SD=1024, CD=512, H=256, HEADS=4, DH=64.
//
// Pipeline (all bf16 intermediates in ws):
//  K0 cvt_w     : fp32->bf16 weight conversion (Wv,Ws,Wc,in_w,out_w,g1w)
//  K1 gemm_ln   : {fv,fs,fc} @ W.T + bias -> LayerNorm -> stack (B*3,256) bf16
//  K4 outproj_k : FUSED qkv-GEMM (was K2) + attention (was K3) + out-proj +
//                 residual + LN + gating MLP -> fused+gates
//
// Ledger: R10 (K3 fused into K4) hit e2e 421 (best). Accounting leaves ~290us
// in K2+K4. K2 only materializes qkv (75MB HBM round-trip) which K4 re-stages;
// qkv is block-local to K4's 48-row tile (qkv[row] = stack[row] @ in_w.T).
// R11: K2 fused into K4 phase 1 -- qkv computed straight into LDS in the
// attention layout. Eliminates K2's launch, 144MB stack re-staging, 75MB qkv
// write, 73MB qkv read, 24MB stack re-stage (stack tile stays resident for
// the residual). Adds in_w staging per block (L2-served) + 768 MFMA/block.

typedef unsigned short u16;
typedef __bf16 bf16x8 __attribute__((ext_vector_type(8)));
typedef float fx4 __attribute__((ext_vector_type(4)));

#define MFMA_BF16(A_, B_, C_) __builtin_amdgcn_mfma_f32_16x16x32_bf16((A_), (B_), (C_), 0, 0, 0)
#define WAIT_VM(N) asm volatile("s_waitcnt vmcnt(" #N ")" ::: "memory")

__device__ __forceinline__ float bf2f(u16 s) {
    union { float f; unsigned u; } c; c.u = ((unsigned)s) << 16; return c.f;
}
__device__ __forceinline__ u16 f2bf(float f) {
    union { float f; unsigned u; } c; c.f = f;
    return (u16)((c.u + 0x7fffu + ((c.u >> 16) & 1u)) >> 16);
}
// a,b are packed bf16 pairs (little-endian: low u16 = even element)
__device__ __forceinline__ float bfpair_dot(unsigned a, unsigned b) {
    union { unsigned u; float f; } al, ah, bl, bh;
    al.u = a << 16; ah.u = a & 0xffff0000u;
    bl.u = b << 16; bh.u = b & 0xffff0000u;
    return al.f * bl.f + ah.f * bh.f;
}
__device__ __forceinline__ void gld16(void* l, const void* g) {
    __builtin_amdgcn_global_load_lds((const __attribute__((address_space(1))) void*)g,
                                     (__attribute__((address_space(3))) void*)l, 16, 0, 0);
}

// ---------------------------------------------------------------- K0: weights
__global__ __launch_bounds__(256) void cvt_w(const float* Wv, const float* Ws, const float* Wc,
                                             const float* inw, const float* outw, const float* g1w,
                                             u16* dst) {
    int idx = blockIdx.x * 256 + threadIdx.x;  // grid covers exactly 1228800
    const float* src; int rel;
    if      (idx <  524288) { src = Wv;   rel = idx; }
    else if (idx <  786432) { src = Ws;   rel = idx -  524288; }
    else if (idx <  917504) { src = Wc;   rel = idx -  786432; }
    else if (idx < 1114112) { src = inw;  rel = idx -  917504; }
    else if (idx < 1179648) { src = outw; rel = idx - 1114112; }
    else                    { src = g1w;  rel = idx - 1179648; }
    dst[idx] = f2bf(src[rel]);
}

// ------------------------------------------------- K1: input GEMM + LayerNorm
// R2-form verbatim (best measured: 119-131us). BM=64, BN=256, BK=32, 4 waves.
// 1D grid of 768 blocks, longest-job-first. Double-buffered LDS + 1-deep
// prefetch, single barrier per K-step.
__global__ __launch_bounds__(256, 3) void gemm_ln(
    const float* fv, const float* fs, const float* fc,
    const u16* wWv, const u16* wWs, const u16* wWc,
    const float* bv, const float* gv, const float* bev,
    const float* bs, const float* gs, const float* bes,
    const float* bc, const float* gc_, const float* bec,
    u16* stack) {
    __shared__ alignas(16) char smem[45568];
    u16* sC = (u16*)smem;
    float* redS = (float*)(smem + 43008);   // [64][4]
    float* redQ = (float*)(smem + 44032);   // [64][4]
    float* mvS  = (float*)(smem + 45056);   // [64][2] mean,rstd

    int bid = blockIdx.x;
    int slot, mblk;
    if (bid < 256)      { slot = 0; mblk = bid; }
    else if (bid < 512) { slot = 1; mblk = bid - 256; }
    else                { slot = 2; mblk = bid - 512; }

    const float* A; const u16* W; const float* bias; const float* gg; const float* be; int K;
    if (slot == 0)      { A = fv; W = wWv; bias = bv; gg = gv;  be = bev; K = 2048; }
    else if (slot == 1) { A = fs; W = wWs; bias = bs; gg = gs;  be = bes; K = 1024; }
    else                { A = fc; W = wWc; bias = bc; gg = gc_; be = bec; K = 512;  }

    int t = threadIdx.x, wv = t >> 6, ln = t & 63, q = ln >> 4, l15 = ln & 15;
    int m0 = mblk * 64;

    fx4 zero = {0.f, 0.f, 0.f, 0.f};
    fx4 acc[4][4];
    #pragma unroll
    for (int mi = 0; mi < 4; ++mi)
        #pragma unroll
        for (int ni = 0; ni < 4; ++ni) acc[mi][ni] = zero;

    int rowA = t >> 2, ca = t & 3;                       // 64 rows x 4 chunks-of-8
    const float* aBase = A + (size_t)(m0 + rowA) * K + ca * 8;
    int sAwOff = rowA * 40 + ca * 8;                     // elem offset within sA buf

    int bN[4], bKc[4], bDst[4];
    #pragma unroll
    for (int i = 0; i < 4; ++i) {
        int d = wv * 256 + i * 64 + ln;
        bN[i] = d >> 2;
        bKc[i] = (d & 3) ^ ((bN[i] >> 1) & 3);
        bDst[i] = (wv * 256 + i * 64) * 16;              // byte offset in sB buf
    }

    int niter = K >> 5;

    // ---- prologue: stage tile 0 into buf 0
    {
        float4 f0 = *(const float4*)(aBase);
        float4 f1 = *(const float4*)(aBase + 4);
        #pragma unroll
        for (int i = 0; i < 4; ++i)
            gld16(smem + 10240 + bDst[i], W + (size_t)bN[i] * K + bKc[i] * 8);
        union { u16 us[8]; uint4 v; } pk;
        pk.us[0] = f2bf(f0.x); pk.us[1] = f2bf(f0.y); pk.us[2] = f2bf(f0.z); pk.us[3] = f2bf(f0.w);
        pk.us[4] = f2bf(f1.x); pk.us[5] = f2bf(f1.y); pk.us[6] = f2bf(f1.z); pk.us[7] = f2bf(f1.w);
        *(uint4*)((u16*)smem + sAwOff) = pk.v;
    }
    __syncthreads();

    for (int kt = 0; kt < niter; ++kt) {
        int cur = kt & 1, nxt_b = (kt + 1) & 1;
        u16* sAc = (u16*)(smem + cur * 5120);
        u16* sBc = (u16*)(smem + 10240 + cur * 16384);
        int has_next = (kt + 1) < niter;

        float4 nf0, nf1;
        if (has_next) {
            nf0 = *(const float4*)(aBase + (kt + 1) * 32);
            nf1 = *(const float4*)(aBase + (kt + 1) * 32 + 4);
            char* sBn = smem + 10240 + nxt_b * 16384;
            #pragma unroll
            for (int i = 0; i < 4; ++i)
                gld16(sBn + bDst[i], W + (size_t)bN[i] * K + (kt + 1) * 32 + bKc[i] * 8);
        }

        bf16x8 af[4], bfr[4];
        #pragma unroll
        for (int mi = 0; mi < 4; ++mi)
            af[mi] = *(const bf16x8*)(sAc + (mi * 16 + l15) * 40 + q * 8);
        #pragma unroll
        for (int ni = 0; ni < 4; ++ni) {
            int n = wv * 64 + ni * 16 + l15;
            int ch = n * 4 + (q ^ ((n >> 1) & 3));
            bfr[ni] = *(const bf16x8*)(sBc + ch * 8);
        }
        #pragma unroll
        for (int mi = 0; mi < 4; ++mi)
            #pragma unroll
            for (int ni = 0; ni < 4; ++ni)
                acc[mi][ni] = MFMA_BF16(af[mi], bfr[ni], acc[mi][ni]);

        if (has_next) {
            union { u16 us[8]; uint4 v; } pk;
            pk.us[0] = f2bf(nf0.x); pk.us[1] = f2bf(nf0.y); pk.us[2] = f2bf(nf0.z); pk.us[3] = f2bf(nf0.w);
            pk.us[4] = f2bf(nf1.x); pk.us[5] = f2bf(nf1.y); pk.us[6] = f2bf(nf1.z); pk.us[7] = f2bf(nf1.w);
            *(uint4*)((u16*)(smem + nxt_b * 5120) + sAwOff) = pk.v;
        }
        __syncthreads();
    }

    // epilogue: bias, LN stats from registers, normalize, write bf16
    float biasv[4], gvv[4], bevv[4];
    #pragma unroll
    for (int ni = 0; ni < 4; ++ni) {
        int col = wv * 64 + ni * 16 + l15;
        biasv[ni] = bias[col]; gvv[ni] = gg[col]; bevv[ni] = be[col];
    }
    #pragma unroll
    for (int mi = 0; mi < 4; ++mi)
        #pragma unroll
        for (int ni = 0; ni < 4; ++ni)
            #pragma unroll
            for (int r = 0; r < 4; ++r) acc[mi][ni][r] += biasv[ni];
    #pragma unroll
    for (int mi = 0; mi < 4; ++mi) {
        #pragma unroll
        for (int r = 0; r < 4; ++r) {
            float s = 0.f, qq = 0.f;
            #pragma unroll
            for (int ni = 0; ni < 4; ++ni) { float x = acc[mi][ni][r]; s += x; qq += x * x; }
            #pragma unroll
            for (int m = 1; m < 16; m <<= 1) { s += __shfl_xor(s, m, 64); qq += __shfl_xor(qq, m, 64); }
            if (l15 == 0) { int rho = mi * 16 + q * 4 + r; redS[rho * 4 + wv] = s; redQ[rho * 4 + wv] = qq; }
        }
    }
    __syncthreads();
    if (t < 64) {
        float s = redS[t * 4] + redS[t * 4 + 1] + redS[t * 4 + 2] + redS[t * 4 + 3];
        float qq = redQ[t * 4] + redQ[t * 4 + 1] + redQ[t * 4 + 2] + redQ[t * 4 + 3];
        float mean = s * (1.f / 256.f);
        float var = qq * (1.f / 256.f) - mean * mean;
        mvS[t * 2] = mean; mvS[t * 2 + 1] = rsqrtf(var + 1e-5f);
    }
    __syncthreads();
    #pragma unroll
    for (int mi = 0; mi < 4; ++mi) {
        #pragma unroll
        for (int r = 0; r < 4; ++r) {
            int rho = mi * 16 + q * 4 + r;
            float mean = mvS[rho * 2], rstd = mvS[rho * 2 + 1];
            #pragma unroll
            for (int ni = 0; ni < 4; ++ni) {
                int col = wv * 64 + ni * 16 + l15;
                float x = (acc[mi][ni][r] - mean) * rstd * gvv[ni] + bevv[ni];
                sC[rho * 256 + col] = f2bf(x);
            }
        }
    }
    __syncthreads();
    u16* outp = stack + (size_t)m0 * 768 + slot * 256;
    #pragma unroll
    for (int it = 0; it < 8; ++it) {
        int idx = t + it * 256;
        int row = idx >> 5, c = idx & 31;
        uint4 v = *(const uint4*)(sC + row * 256 + c * 8);
        *(uint4*)(outp + (size_t)row * 768 + c * 8) = v;
    }
}

// ---- K4: FUSED qkv-GEMM + attention + out-proj + residual + LN + gating
// BM=48 rows = 16 b's per block, grid 1024, 512 threads (8 waves).
// Phase 1: stack tile [48][256] staged once (swizzled, kept resident for the
//   residual); 24 counted-vmcnt steps (3 n-panels x 8 kt, 3-buffer in_w
//   slices) compute qkv[48][768] -> LDS in the attention layout
//   (qk [48][512], v [48][256]). qkv never touches global memory.
// Phase 2: attention fully in-LDS -> swizzled ctx in r1 (overlays dead qk).
// Phase 3: out-proj GEMM (counted-vmcnt out_w slices) + residual from the
//   resident stack tile + LN + gating MLP + outputs.
// LDS map: stackS @0 (24576) | qk @24576 (49152; r1 overlays first 24576
// after scores) | v @73728 (24576; epilogue red/h1/lg/gate overlay) |
// sB @98304 (3x16384) | sS @147456 (2304). Total 149760.
__global__ __launch_bounds__(512) void outproj_k(
    const u16* stack, const u16* Win, const float* in_b,
    const u16* W, const float* out_b,
    const float* gn, const float* gb, const u16* g1w, const float* g1b,
    const float* g2w, const float* g2b, float* outF, float* outG) {
    __shared__ alignas(16) char smem[149760];
    u16* stackS = (u16*)smem;                     // [48][32ch] swizzled
    u16* qk  = (u16*)(smem + 24576);              // [48][512]
    u16* r1  = (u16*)(smem + 24576);              // overlay after scores
    u16* vb  = (u16*)(smem + 73728);              // [48][256]
    float* sS   = (float*)(smem + 147456);        // 576 scores
    float* redS = (float*)(smem + 73728);         // [48][8] (epilogue overlay on v)
    float* redQ = (float*)(smem + 75264);         // [48][8]
    float* mvS  = (float*)(smem + 76800);         // [48][2]
    float* h1S  = (float*)(smem + 77184);         // [16][64]
    float* lgS  = (float*)(smem + 81280);         // 48 logits
    float* gateS= (float*)(smem + 81472);         // 48 gates

    int t = threadIdx.x, wv = t >> 6, ln = t & 63, q = ln >> 4, l15 = ln & 15;
    int gr0 = blockIdx.x * 48, b0 = blockIdx.x * 16;

    // staging maps
    // stackS: 1536 chunks, chunk d: row=d>>5, pos p=d&31 holds k-chunk p^(row&7)
    int stR[3], stKc[3];
    #pragma unroll
    for (int i = 0; i < 3; ++i) {
        int d = i * 512 + t;
        stR[i] = d >> 5;
        stKc[i] = (d & 31) ^ (stR[i] & 7);
    }
    // W slices (in_w / out_w): 1024 chunks, chunk d: n=d>>2, pos p=d&3 holds
    // k-chunk p^((n>>1)&3). 2 chunks/thread.
    int bN[2], bKc[2];
    #pragma unroll
    for (int i = 0; i < 2; ++i) {
        int d = i * 512 + t;
        bN[i] = d >> 2;
        bKc[i] = (d & 3) ^ ((bN[i] >> 1) & 3);
    }

#define SLICE_IN(s_, buf_)                                                            \
    {                                                                                 \
        int np_ = (s_) >> 3, kt_ = (s_) & 7;                                          \
        char* dst_ = smem + 98304 + (buf_) * 16384;                                   \
        _Pragma("unroll")                                                             \
        for (int i_ = 0; i_ < 2; ++i_)                                                \
            gld16(dst_ + (i_ * 512 + t) * 16,                                         \
                  Win + (size_t)(np_ * 256 + bN[i_]) * 256 + kt_ * 32 + bKc[i_] * 8); \
    }
#define SLICE_OUT(kt_, buf_)                                                          \
    {                                                                                 \
        char* dst_ = smem + 98304 + (buf_) * 16384;                                   \
        _Pragma("unroll")                                                             \
        for (int i_ = 0; i_ < 2; ++i_)                                                \
            gld16(dst_ + (i_ * 512 + t) * 16,                                         \
                  W + (size_t)bN[i_] * 256 + (kt_) * 32 + bKc[i_] * 8);               \
    }

    fx4 zero = {0.f, 0.f, 0.f, 0.f};

    // ---- phase 1: qkv = stackTile @ in_w.T + in_b, straight into LDS ----
    // prologue: stack tile (3 loads/thread) + slices 0,1 (2 each)
    #pragma unroll
    for (int i = 0; i < 3; ++i)
        gld16((char*)stackS + (i * 512 + t) * 16,
              stack + (size_t)(gr0 + stR[i]) * 256 + stKc[i] * 8);
    SLICE_IN(0, 0);
    SLICE_IN(1, 1);

    {
        fx4 acc[3][2];
        #pragma unroll
        for (int mi = 0; mi < 3; ++mi)
            #pragma unroll
            for (int ni = 0; ni < 2; ++ni) acc[mi][ni] = zero;

        int cb = 0;
        for (int s = 0; s < 24; ++s) {
            if (s < 23) { WAIT_VM(2); } else { WAIT_VM(0); }
            __builtin_amdgcn_sched_barrier(0);
            __builtin_amdgcn_s_barrier();
            __builtin_amdgcn_sched_barrier(0);
            int nb = cb + 2; if (nb >= 3) nb -= 3;
            if (s + 2 < 24) SLICE_IN(s + 2, nb);

            int kt = s & 7;
            const u16* sBc = (const u16*)(smem + 98304 + cb * 16384);
            bf16x8 af[3], bfr[2];
            #pragma unroll
            for (int mi = 0; mi < 3; ++mi) {
                int row = mi * 16 + l15;
                af[mi] = *(const bf16x8*)(stackS + (row * 32 + ((kt * 4 + q) ^ (row & 7))) * 8);
            }
            #pragma unroll
            for (int ni = 0; ni < 2; ++ni) {
                int n = wv * 32 + ni * 16 + l15;
                int ch = n * 4 + (q ^ ((n >> 1) & 3));
                bfr[ni] = *(const bf16x8*)(sBc + ch * 8);
            }
            __builtin_amdgcn_s_setprio(1);
            #pragma unroll
            for (int mi = 0; mi < 3; ++mi)
                #pragma unroll
                for (int ni = 0; ni < 2; ++ni)
                    acc[mi][ni] = MFMA_BF16(af[mi], bfr[ni], acc[mi][ni]);
            __builtin_amdgcn_s_setprio(0);

            if (kt == 7) {  // panel np = s>>3 complete: bias + write to LDS qkv
                int np = s >> 3;
                #pragma unroll
                for (int ni = 0; ni < 2; ++ni) {
                    int cl = wv * 32 + ni * 16 + l15;
                    float bias = in_b[np * 256 + cl];
                    #pragma unroll
                    for (int mi = 0; mi < 3; ++mi)
                        #pragma unroll
                        for (int r = 0; r < 4; ++r) {
                            int rl = mi * 16 + q * 4 + r;
                            u16 val = f2bf(acc[mi][ni][r] + bias);
                            if (np < 2) qk[rl * 512 + np * 256 + cl] = val;
                            else        vb[rl * 256 + cl] = val;
                        }
                }
                #pragma unroll
                for (int mi = 0; mi < 3; ++mi)
                    #pragma unroll
                    for (int ni = 0; ni < 2; ++ni) acc[mi][ni] = zero;
            }
            cb += 1; if (cb >= 3) cb -= 3;
        }
    }
    __syncthreads();   // qk/v writes visible to all waves

    // ---- phase 2: attention in-LDS ----
    // scores: 576 items = 16b*4h*9(i,j)
    #pragma unroll
    for (int it = 0; it < 2; ++it) {
        int idx = t + it * 512;
        if (idx < 576) {
            int b = idx / 36, rem = idx % 36, h = rem / 9, pp = rem % 9, i = pp / 3, j = pp % 3;
            const u16* qp = qk + (b * 3 + i) * 512 + h * 64;
            const u16* kp = qk + (b * 3 + j) * 512 + 256 + h * 64;
            float acc = 0.f;
            #pragma unroll
            for (int c = 0; c < 8; ++c) {
                uint4 qa = *(const uint4*)(qp + c * 8);
                uint4 ka = *(const uint4*)(kp + c * 8);
                acc += bfpair_dot(qa.x, ka.x) + bfpair_dot(qa.y, ka.y) +
                       bfpair_dot(qa.z, ka.z) + bfpair_dot(qa.w, ka.w);
            }
            sS[idx] = acc * 0.125f;  // /sqrt(64)
        }
    }
    __syncthreads();
    if (t < 192) {  // softmax over j, t = b*12 + h*3 + i
        int b3 = t * 3;
        float s0 = sS[b3], s1 = sS[b3 + 1], s2 = sS[b3 + 2];
        float m = fmaxf(s0, fmaxf(s1, s2));
        float e0 = __expf(s0 - m), e1 = __expf(s1 - m), e2 = __expf(s2 - m);
        float inv = 1.f / (e0 + e1 + e2);
        sS[b3] = e0 * inv; sS[b3 + 1] = e1 * inv; sS[b3 + 2] = e2 * inv;
    }
    __syncthreads();
    // ctx -> r1 (swizzled, overlays dead qk): 1536 items = 16b*3i*32 chunks
    #pragma unroll
    for (int it = 0; it < 3; ++it) {
        int idx = t + it * 512;
        int b = idx / 96, rem = idx % 96, i = rem / 32, c = rem & 31, h = c >> 3;
        int pbase = b * 36 + h * 9 + i * 3;
        float o[8];
        #pragma unroll
        for (int e = 0; e < 8; ++e) o[e] = 0.f;
        #pragma unroll
        for (int j = 0; j < 3; ++j) {
            float p = sS[pbase + j];
            uint4 va = *(const uint4*)(vb + (b * 3 + j) * 256 + c * 8);
            unsigned uu[4] = {va.x, va.y, va.z, va.w};
            #pragma unroll
            for (int pr = 0; pr < 4; ++pr) {
                union { unsigned u; float f; } lo, hi;
                lo.u = uu[pr] << 16; hi.u = uu[pr] & 0xffff0000u;
                o[2 * pr]     += p * lo.f;
                o[2 * pr + 1] += p * hi.f;
            }
        }
        union { u16 us[8]; uint4 v; } pk;
        #pragma unroll
        for (int e = 0; e < 8; ++e) pk.us[e] = f2bf(o[e]);
        int row = b * 3 + i;
        *(uint4*)(r1 + (row * 32 + (c ^ (row & 7))) * 8) = pk.v;
    }
    __syncthreads();

    // ---- phase 3: out-proj GEMM (counted-vmcnt), A = r1 (swizzled ctx) ----
    fx4 acc2[3][2];
    #pragma unroll
    for (int mi = 0; mi < 3; ++mi)
        #pragma unroll
        for (int ni = 0; ni < 2; ++ni) acc2[mi][ni] = zero;

    SLICE_OUT(0, 0);
    SLICE_OUT(1, 1);
    {
        int cb = 0;
        for (int kt = 0; kt < 8; ++kt) {
            if (kt < 7) { WAIT_VM(2); } else { WAIT_VM(0); }
            __builtin_amdgcn_sched_barrier(0);
            __builtin_amdgcn_s_barrier();
            __builtin_amdgcn_sched_barrier(0);
            int nb = cb + 2; if (nb >= 3) nb -= 3;
            if (kt + 2 < 8) SLICE_OUT(kt + 2, nb);

            const u16* sBc = (const u16*)(smem + 98304 + cb * 16384);
            bf16x8 af[3], bfr[2];
            #pragma unroll
            for (int mi = 0; mi < 3; ++mi) {
                int row = mi * 16 + l15;
                af[mi] = *(const bf16x8*)(r1 + (row * 32 + ((kt * 4 + q) ^ (row & 7))) * 8);
            }
            #pragma unroll
            for (int ni = 0; ni < 2; ++ni) {
                int n = wv * 32 + ni * 16 + l15;
                int ch = n * 4 + (q ^ ((n >> 1) & 3));
                bfr[ni] = *(const bf16x8*)(sBc + ch * 8);
            }
            __builtin_amdgcn_s_setprio(1);
            #pragma unroll
            for (int mi = 0; mi < 3; ++mi)
                #pragma unroll
                for (int ni = 0; ni < 2; ++ni)
                    acc2[mi][ni] = MFMA_BF16(af[mi], bfr[ni], acc2[mi][ni]);
            __builtin_amdgcn_s_setprio(0);
            cb += 1; if (cb >= 3) cb -= 3;
        }
    }
    __syncthreads();   // done reading sB/r1(ctx) before overlays

    // residual (from resident stack tile) + bias, LN stats
    float obv[2], gnv[2], gbv[2];
    #pragma unroll
    for (int ni = 0; ni < 2; ++ni) {
        int col = wv * 32 + ni * 16 + l15;
        obv[ni] = out_b[col]; gnv[ni] = gn[col]; gbv[ni] = gb[col];
    }
    #pragma unroll
    for (int mi = 0; mi < 3; ++mi)
        #pragma unroll
        for (int ni = 0; ni < 2; ++ni)
            #pragma unroll
            for (int r = 0; r < 4; ++r) {
                int rho = mi * 16 + q * 4 + r;
                int col = wv * 32 + ni * 16 + l15;
                u16 sv = stackS[(rho * 32 + ((col >> 3) ^ (rho & 7))) * 8 + (col & 7)];
                acc2[mi][ni][r] += obv[ni] + bf2f(sv);
            }
    #pragma unroll
    for (int mi = 0; mi < 3; ++mi) {
        #pragma unroll
        for (int r = 0; r < 4; ++r) {
            float s = 0.f, qq = 0.f;
            #pragma unroll
            for (int ni = 0; ni < 2; ++ni) { float x = acc2[mi][ni][r]; s += x; qq += x * x; }
            #pragma unroll
            for (int m = 1; m < 16; m <<= 1) { s += __shfl_xor(s, m, 64); qq += __shfl_xor(qq, m, 64); }
            if (l15 == 0) { int rho = mi * 16 + q * 4 + r; redS[rho * 8 + wv] = s; redQ[rho * 8 + wv] = qq; }
        }
    }
    __syncthreads();
    if (t < 48) {
        float s = 0.f, qq = 0.f;
        #pragma unroll
        for (int i = 0; i < 8; ++i) { s += redS[t * 8 + i]; qq += redQ[t * 8 + i]; }
        float mean = s * (1.f / 256.f);
        float var = qq * (1.f / 256.f) - mean * mean;
        mvS[t * 2] = mean; mvS[t * 2 + 1] = rsqrtf(var + 1e-5f);
    }
    __syncthreads();
    // normalize -> r1 attended layout ([16b][96 chunks], chunk = bl*96 + (kidx^(bl&7)))
    #pragma unroll
    for (int mi = 0; mi < 3; ++mi) {
        #pragma unroll
        for (int r = 0; r < 4; ++r) {
            int rho = mi * 16 + q * 4 + r;
            float mean = mvS[rho * 2], rstd = mvS[rho * 2 + 1];
            int bl = rho / 3, sl = rho - bl * 3;
            #pragma unroll
            for (int ni = 0; ni < 2; ++ni) {
                int col = wv * 32 + ni * 16 + l15;
                float x = (acc2[mi][ni][r] - mean) * rstd * gnv[ni] + gbv[ni];
                int k = sl * 256 + col;
                int kidx = k >> 3, wn = k & 7;
                r1[(bl * 96 + (kidx ^ (bl & 7))) * 8 + wn] = f2bf(x);
            }
        }
    }
    __syncthreads();
    // gating MFMA: h1[16 b][64] = attended_flat(16x768) @ g1w.T
    // waves 0..3 each own 16 cols; waves 4..7 idle here (no barriers inside)
    if (wv < 4) {
        fx4 ag = zero;
        for (int kt = 0; kt < 24; ++kt) {
            int bl = l15;
            int kidx = kt * 4 + q;
            bf16x8 afr = *(const bf16x8*)(r1 + (bl * 96 + (kidx ^ (bl & 7))) * 8);
            int n = wv * 16 + l15;
            bf16x8 bfr2 = *(const bf16x8*)(g1w + (size_t)n * 768 + kt * 32 + q * 8);
            ag = MFMA_BF16(afr, bfr2, ag);
        }
        #pragma unroll
        for (int r = 0; r < 4; ++r) {
            int bl = q * 4 + r, n = wv * 16 + l15;
            float x = ag[r] + g1b[n];
            h1S[bl * 64 + n] = 0.5f * x * (1.f + erff(x * 0.70710678118f));
        }
    }
    __syncthreads();
    if (t < 48) {  // logits: t = bl*3 + s
        int bl = t / 3, s = t - bl * 3;
        float a = g2b[s];
        #pragma unroll
        for (int k = 0; k < 64; ++k) a += h1S[bl * 64 + k] * g2w[s * 64 + k];
        lgS[t] = a;
    }
    __syncthreads();
    if (t < 48) {
        int bl = t / 3, s = t - bl * 3;
        float l0 = lgS[bl * 3], l1 = lgS[bl * 3 + 1], l2 = lgS[bl * 3 + 2];
        float m = fmaxf(l0, fmaxf(l1, l2));
        float e0 = __expf(l0 - m), e1 = __expf(l1 - m), e2 = __expf(l2 - m);
        float inv = 1.f / (e0 + e1 + e2);
        float gsel = ((s == 0) ? e0 : (s == 1) ? e1 : e2) * inv;
        gateS[t] = gsel;
        outG[(size_t)(b0 + bl) * 3 + s] = gsel;
    }
    __syncthreads();
    // fused = sum_s gate[s] * attended[s] : 512 items = 16b x 32 chunks
    {
        int b = t >> 5, c = t & 31;
        float g0 = gateS[b * 3], g1 = gateS[b * 3 + 1], g2 = gateS[b * 3 + 2];
        float o[8];
        #pragma unroll
        for (int e = 0; e < 8; ++e) o[e] = 0.f;
        #pragma unroll
        for (int s = 0; s < 3; ++s) {
            float gw = (s == 0) ? g0 : (s == 1) ? g1 : g2;
            int kidx = s * 32 + c;
            uint4 raw = *(const uint4*)(r1 + (b * 96 + (kidx ^ (b & 7))) * 8);
            unsigned uu[4] = {raw.x, raw.y, raw.z, raw.w};
            #pragma unroll
            for (int pr = 0; pr < 4; ++pr) {
                union { unsigned u; float f; } lo, hi;
                lo.u = uu[pr] << 16; hi.u = uu[pr] & 0xffff0000u;
                o[2 * pr]     += gw * lo.f;
                o[2 * pr + 1] += gw * hi.f;
            }
        }
        float* op = outF + (size_t)(b0 + b) * 256 + c * 8;
        float4 v0; v0.x = o[0]; v0.y = o[1]; v0.z = o[2]; v0.w = o[3];
        float4 v1; v1.x = o[4]; v1.y = o[5]; v1.z = o[6]; v1.w = o[7];
        *(float4*)op = v0;
        *(float4*)(op + 4) = v1;
    }
#undef SLICE_IN
#undef SLICE_OUT
}

extern "C" void kernel_launch(void* const* d_in, const int* in_sizes, int n_in,
                              void* d_out, int out_size, void* d_ws, size_t ws_size,
                              hipStream_t stream) {
    (void)in_sizes; (void)n_in; (void)out_size; (void)ws_size;
    const float* fv   = (const float*)d_in[0];
    const float* fs   = (const float*)d_in[1];
    const float* fc   = (const float*)d_in[2];
    const float* Wv   = (const float*)d_in[3];
    const float* bv   = (const float*)d_in[4];
    const float* gv   = (const float*)d_in[5];
    const float* bev  = (const float*)d_in[6];
    const float* Ws   = (const float*)d_in[7];
    const float* bs   = (const float*)d_in[8];
    const float* gs   = (const float*)d_in[9];
    const float* bes  = (const float*)d_in[10];
    const float* Wc   = (const float*)d_in[11];
    const float* bc   = (const float*)d_in[12];
    const float* gc_  = (const float*)d_in[13];
    const float* bec  = (const float*)d_in[14];
    const float* in_w = (const float*)d_in[15];
    const float* in_b = (const float*)d_in[16];
    const float* out_w= (const float*)d_in[17];
    const float* out_b= (const float*)d_in[18];
    const float* gn   = (const float*)d_in[19];
    const float* gb   = (const float*)d_in[20];
    const float* g1w  = (const float*)d_in[21];
    const float* g1b  = (const float*)d_in[22];
    const float* g2w  = (const float*)d_in[23];
    const float* g2b  = (const float*)d_in[24];

    u16* w0    = (u16*)d_ws;
    u16* wWv   = w0;               // 524288
    u16* wWs   = w0 + 524288;      // 262144
    u16* wWc   = w0 + 786432;      // 131072
    u16* wIn   = w0 + 917504;      // 196608
    u16* wOut  = w0 + 1114112;     // 65536
    u16* wG1   = w0 + 1179648;     // 49152
    u16* stack = w0 + 1228800;     // 49152*256
    float* outF = (float*)d_out;
    float* outG = outF + (size_t)16384 * 256;

    cvt_w<<<4800, 256, 0, stream>>>(Wv, Ws, Wc, in_w, out_w, g1w, w0);
    gemm_ln<<<768, 256, 0, stream>>>(fv, fs, fc, wWv, wWs, wWc,
                                     bv, gv, bev, bs, gs, bes, bc, gc_, bec, stack);
    outproj_k<<<1024, 512, 0, stream>>>(stack, wIn, in_b, wOut, out_b, gn, gb,
                                        wG1, g1b, g2w, g2b, outF, outG);
}